// Round 10
// baseline (488.902 us; speedup 1.0000x reference)
//
#include <hip/hip_runtime.h>

// ---------------------------------------------------------------------------
// PointNet++ SA-MSG on MI355X.
// KNN (top-128, reg-cached keys + rank-scatter) -> moments (L0 BN stats) ->
// fused2 (L1+L2 raw stats) -> fused3 (L1+L2 recompute + L3 ot-split across
// waves, double-buffered a2, one barrier/kc) -> finalize -> outpool.
// Conv biases are BN no-ops and dropped.  bf16 MFMA 16x16x32, fp32 accum.
// ---------------------------------------------------------------------------

typedef __attribute__((ext_vector_type(8))) short bf16x8;   // 8 bf16 = 4 VGPR
typedef __attribute__((ext_vector_type(4))) float f32x4;

__device__ __forceinline__ float bf2f(unsigned short u) {
  return __uint_as_float(((unsigned)u) << 16);
}
__device__ __forceinline__ unsigned short f2bf(float f) {
  unsigned u = __float_as_uint(f);
  unsigned r = (u + 0x7FFFu + ((u >> 16) & 1u)) >> 16;  // RNE
  return (unsigned short)r;
}
__device__ __forceinline__ unsigned pack2(float a, float b) {
  return (unsigned)f2bf(a) | (((unsigned)f2bf(b)) << 16);
}

struct PWB { const float* W[3][3]; };

// ---------------- zero stats+moments ----------------
__global__ void zero_stats_kernel(float* __restrict__ s) {
  for (int i = threadIdx.x; i < 4704; i += 256) s[i] = 0.f;
}

// ---------------- out0 = xyz[:, :, :1024] ----------------
__global__ void copyxyz_kernel(const float* __restrict__ xyz, float* __restrict__ out) {
  int t = blockIdx.x * 256 + threadIdx.x;  // 24576 total
  int b = t / 3072;
  int r = t - b * 3072;
  int c = r >> 10, s = r & 1023;
  out[t] = xyz[(size_t)(b * 3 + c) * 8192 + s];
}

// ---------------- KNN: top-128 by (d, idx) ----------------
// Keys cached in registers (32/thread, statically unrolled). Histogram select
// -> collect candidates -> rank-by-counting scatter (exact numpy tie-break).
__global__ __launch_bounds__(256) void knn_kernel(const float* __restrict__ xyz,
                                                  int* __restrict__ idxout) {
  __shared__ unsigned hist[4096];            // 16 KB
  __shared__ unsigned long long sbuf[512];   // 4 KB
  __shared__ unsigned wsum[4];
  __shared__ unsigned selB, selC;
  __shared__ int cnt;

  const int tid = threadIdx.x;
  const int lane = tid & 63;
  const int wid = tid >> 6;
  const int bs = blockIdx.x;
  const int b = bs >> 10, s = bs & 1023;
  const float* xb = xyz + (size_t)b * 3 * 8192;

  const float q0 = xb[s], q1 = xb[8192 + s], q2 = xb[16384 + s];
  const float qq =
      __fadd_rn(__fadd_rn(__fmul_rn(q0, q0), __fmul_rn(q1, q1)), __fmul_rn(q2, q2));

  auto ckey = [&](int n) -> unsigned {
    float p0 = xb[n], p1 = xb[8192 + n], p2 = xb[16384 + n];
    float pp = __fadd_rn(__fadd_rn(__fmul_rn(p0, p0), __fmul_rn(p1, p1)), __fmul_rn(p2, p2));
    float dot =
        __fadd_rn(__fadd_rn(__fmul_rn(q0, p0), __fmul_rn(q1, p1)), __fmul_rn(q2, p2));
    float dd = __fadd_rn(__fadd_rn(qq, pp), __fmul_rn(-2.f, dot));
    unsigned uu = __float_as_uint(dd);
    return (uu & 0x80000000u) ? ~uu : (uu | 0x80000000u);
  };

  auto select_bin = [&](int rank) {
    unsigned psum = 0;
#pragma unroll
    for (int i = 0; i < 16; ++i) psum += hist[tid * 16 + i];
    unsigned sc = psum;
#pragma unroll
    for (int d = 1; d < 64; d <<= 1) {
      unsigned v = __shfl_up(sc, d);
      if (lane >= d) sc += v;
    }
    if (lane == 63) wsum[wid] = sc;
    __syncthreads();
    unsigned excl = sc - psum;
#pragma unroll
    for (int w2 = 0; w2 < 3; ++w2)
      if (w2 < wid) excl += wsum[w2];
    unsigned incl = excl + psum;
    if ((unsigned)rank >= excl && (unsigned)rank < incl) {
      unsigned cum = excl;
      int bsel = tid * 16;
#pragma unroll
      for (int i = 0; i < 16; ++i) {
        unsigned h = hist[tid * 16 + i];
        if (cum + h > (unsigned)rank) { bsel = tid * 16 + i; break; }
        cum += h;
      }
      selB = (unsigned)bsel;
      selC = cum;
    }
    __syncthreads();
  };

  for (int i = tid; i < 4096; i += 256) hist[i] = 0;
  if (tid == 0) cnt = 0;
  __syncthreads();

  // pass A: compute keys once (registers), histogram bits [31:20]
  unsigned kreg[32];
#pragma unroll
  for (int i = 0; i < 32; ++i) {
    kreg[i] = ckey(tid + i * 256);
    atomicAdd(&hist[kreg[i] >> 20], 1u);
  }
  __syncthreads();

  select_bin(127);
  const unsigned B1 = selB, c1 = selC;
  const unsigned h1 = hist[B1];
  unsigned T24;
  if (c1 + h1 <= 512) {
    T24 = (B1 << 12) | 0xFFFu;  // whole bin (common case)
  } else {
    // rare: refine on bits [19:8] within bin B1 (keys already in registers)
    __syncthreads();
    for (int i = tid; i < 4096; i += 256) hist[i] = 0;
    __syncthreads();
#pragma unroll
    for (int i = 0; i < 32; ++i)
      if ((kreg[i] >> 20) == B1) atomicAdd(&hist[(kreg[i] >> 8) & 0xFFFu], 1u);
    __syncthreads();
    select_bin(127 - (int)c1);
    T24 = (B1 << 12) | selB;
  }

  // collect candidates (superset of top-128), composite (key<<13)|idx
#pragma unroll
  for (int i = 0; i < 32; ++i) {
    unsigned key = kreg[i];
    if ((key >> 8) <= T24) {
      int pos = atomicAdd(&cnt, 1);
      if (pos < 512) sbuf[pos] = (((unsigned long long)key) << 13) | (unsigned)(tid + i * 256);
    }
  }
  __syncthreads();
  const int cc = cnt < 512 ? cnt : 512;

  // rank-by-counting: keys distinct -> exact rank; write top-128 by rank.
  for (int e = tid; e < cc; e += 256) {
    const unsigned long long mykey = sbuf[e];
    int rank = 0;
    for (int j = 0; j < cc; ++j) rank += (sbuf[j] < mykey) ? 1 : 0;  // LDS broadcast
    if (rank < 128) idxout[(size_t)bs * 128 + rank] = (int)(mykey & 0x1FFFu);
  }
}

// ---------------- moment pass: per-segment Σv, Σv⊗v over gathered sets -----
__global__ __launch_bounds__(256) void moment_kernel(const float* __restrict__ xyz,
                                                     const float* __restrict__ pts,
                                                     const int* __restrict__ idx,
                                                     float* __restrict__ mom) {
  __shared__ float msum[81];
  const int tid = threadIdx.x;
  for (int i = tid; i < 81; i += 256) msum[i] = 0.f;
  __syncthreads();
  const int b = blockIdx.y;
  const int s = blockIdx.x * 32 + (tid >> 3);
  const int kseg = tid & 7;
  const int seg = kseg == 0 ? 0 : (kseg == 1 ? 1 : 2);
  const float* xb = xyz + (size_t)b * 24576;
  const float* pb = pts + (size_t)b * 24576;
  const int* ip = idx + (((size_t)b * 1024 + s) << 7) + kseg * 16;
  const float q0 = xb[s], q1 = xb[8192 + s], q2 = xb[16384 + s];
  float a[27];
#pragma unroll
  for (int i = 0; i < 27; ++i) a[i] = 0.f;
#pragma unroll 4
  for (int kk = 0; kk < 16; ++kk) {
    int j = ip[kk];
    float v[6];
    v[0] = pb[j]; v[1] = pb[8192 + j]; v[2] = pb[16384 + j];
    v[3] = xb[j] - q0; v[4] = xb[8192 + j] - q1; v[5] = xb[16384 + j] - q2;
    int p = 6;
#pragma unroll
    for (int aa = 0; aa < 6; ++aa) {
      a[aa] += v[aa];
#pragma unroll
      for (int cc = aa; cc < 6; ++cc) a[p++] = fmaf(v[aa], v[cc], a[p]);
    }
  }
#pragma unroll
  for (int i = 0; i < 27; ++i) atomicAdd(&msum[seg * 27 + i], a[i]);
  __syncthreads();
  for (int i = tid; i < 81; i += 256) atomicAdd(&mom[i], msum[i]);
}

// ---------------- finalize layer-0 stats from moments ----------------
__global__ void finalize0_kernel(const float* __restrict__ mom, float* __restrict__ stats,
                                 const float* W00, const float* G00, const float* BB00,
                                 const float* W10, const float* G10, const float* BB10,
                                 const float* W20, const float* G20, const float* BB20) {
  __shared__ float S[3][27];
  const int t = threadIdx.x;
  if (t < 27) {
    float p0 = mom[t], p1 = mom[27 + t], p2 = mom[54 + t];
    S[0][t] = p0;
    S[1][t] = p0 + p1;
    S[2][t] = p0 + p1 + p2;
  }
  __syncthreads();
  if (t >= 160) return;
  int scale, ch;
  const float *W, *G, *BB;
  float N;
  if (t < 32) { scale = 0; ch = t; W = W00; G = G00; BB = BB00; N = 131072.f; }
  else if (t < 96) { scale = 1; ch = t - 32; W = W10; G = G10; BB = BB10; N = 262144.f; }
  else { scale = 2; ch = t - 96; W = W20; G = G20; BB = BB20; N = 1048576.f; }
  float w[6];
#pragma unroll
  for (int c = 0; c < 6; ++c) w[c] = W[ch * 6 + c];
  const float* Sv = S[scale];
  float wS1 = 0.f;
#pragma unroll
  for (int c = 0; c < 6; ++c) wS1 = fmaf(w[c], Sv[c], wS1);
  float quad = 0.f;
  int p = 6;
#pragma unroll
  for (int aa = 0; aa < 6; ++aa)
#pragma unroll
    for (int cc = aa; cc < 6; ++cc) {
      float coef = (aa == cc) ? w[aa] * w[aa] : 2.f * w[aa] * w[cc];
      quad = fmaf(coef, Sv[p++], quad);
    }
  float mean = wS1 / N;
  float var = quad / N - mean * mean;
  float sc = G[ch] / sqrtf(var + 1e-5f);
  stats[scale * 1536 + 256 + ch] = sc;
  stats[scale * 1536 + 384 + ch] = BB[ch] - mean * sc;
}

// ---------------- MFMA helpers ----------------
// 16x16x32: A: lane A[l&15][(l>>4)*8+i]; B: B[(l>>4)*8+i][l&15];
// D: row=(l>>4)*4+r, col=l&15.
template <int CIN, int COUT, int CINP>
__device__ __forceinline__ void mfma_layer(const unsigned short* __restrict__ act,
                                           const unsigned short* __restrict__ wl,
                                           int m, int g, int pbase, f32x4* acc) {
#pragma unroll
  for (int ot = 0; ot < COUT / 16; ++ot) acc[ot] = (f32x4)(0.f);
#pragma unroll
  for (int ks = 0; ks < CIN / 32; ++ks) {
    const bf16x8 bfrag = *(const bf16x8*)(act + (pbase + m) * CINP + ks * 32 + g * 8);
#pragma unroll
    for (int ot = 0; ot < COUT / 16; ++ot) {
      const bf16x8 afrag = *(const bf16x8*)(wl + (ot * 16 + m) * CINP + ks * 32 + g * 8);
      acc[ot] = __builtin_amdgcn_mfma_f32_16x16x32_bf16(afrag, bfrag, acc[ot], 0, 0, 0);
    }
  }
}

template <int COUT, int COUTP>
__device__ __forceinline__ void norm_store(unsigned short* __restrict__ dst,
                                           const float* __restrict__ stn,
                                           int m, int g, int pbase, const f32x4* acc) {
#pragma unroll
  for (int ot = 0; ot < COUT / 16; ++ot) {
    const int ch = ot * 16 + g * 4;
    f32x4 sc = *(const f32x4*)(stn + ch);
    f32x4 sh = *(const f32x4*)(stn + COUT + ch);
    float v0 = fmaxf(fmaf(acc[ot][0], sc[0], sh[0]), 0.f);
    float v1 = fmaxf(fmaf(acc[ot][1], sc[1], sh[1]), 0.f);
    float v2 = fmaxf(fmaf(acc[ot][2], sc[2], sh[2]), 0.f);
    float v3 = fmaxf(fmaf(acc[ot][3], sc[3], sh[3]), 0.f);
    uint2 pv = make_uint2(pack2(v0, v1), pack2(v2, v3));
    *(uint2*)(dst + (pbase + m) * COUTP + ch) = pv;
  }
}

// ---------------- fused2: L1 -> norm -> L2, raw h1 stats ----------------
template <int C1, int C2, int K>
__device__ __forceinline__ void fused2_body(
    const float* __restrict__ xyz, const float* __restrict__ pts,
    const int* __restrict__ idx,
    const float* __restrict__ W0g, const float* __restrict__ W1g,
    float* __restrict__ sb, char* __restrict__ smem) {
  constexpr int C1P = C1 + 8;
  constexpr int WL1E = C2 * C1P;
  constexpr int ACT1E = 64 * C1P;
  constexpr int EPIB = C2 * 2 * 4;
  constexpr int ACTB = (ACT1E * 2 > EPIB) ? ACT1E * 2 : EPIB;

  unsigned short* wl1 = (unsigned short*)smem;
  unsigned short* act1 = wl1 + WL1E;
  float* st0n = (float*)(smem + WL1E * 2 + ACTB);
  float* statbuf = (float*)act1;  // epilogue overlay [2*C2]
  float* stOut = sb + 512;

  const int tid = threadIdx.x;
  const int lane = tid & 63;
  const int w = tid >> 6;
  const int m = lane & 15, g = lane >> 4;
  const int s0 = blockIdx.x * 8;
  const int b = blockIdx.y;
  const int pbase = w * 16;

  const int p = pbase + m;
  const int kl = p >> 3;
  const int s = s0 + (p & 7);
  const float* xb = xyz + (size_t)b * 24576;
  const float* pb = pts + (size_t)b * 24576;
  const int* idxp = idx + (((size_t)b * 1024 + s) << 7);
  float cx0 = 0.f, cx1 = 0.f, cx2 = 0.f;
  if (g == 0) {
    cx0 = xb[s];
    cx1 = xb[8192 + s];
    cx2 = xb[16384 + s];
  }

  constexpr int NKC = K / 8;
  float pf[6] = {0, 0, 0, 0, 0, 0};
  int jB = 0;
  if (g == 0) {
    int j0 = idxp[kl];
    pf[0] = pb[j0]; pf[1] = pb[8192 + j0]; pf[2] = pb[16384 + j0];
    pf[3] = xb[j0]; pf[4] = xb[8192 + j0]; pf[5] = xb[16384 + j0];
    jB = idxp[(NKC > 1 ? 8 : 0) + kl];
  }

  for (int i = tid; i < C2 * C1; i += 256) {
    int o = i / C1, c = i - o * C1;
    wl1[o * C1P + c] = f2bf(W1g[i]);
  }
  for (int i = tid; i < C1; i += 256) {
    st0n[i] = sb[256 + i];
    st0n[C1 + i] = sb[384 + i];
  }

  bf16x8 w0f[C1 / 16];
#pragma unroll
  for (int ot = 0; ot < C1 / 16; ++ot) {
    bf16x8 a = (bf16x8)(short)0;
    if (g == 0) {
      const float* wr = W0g + (ot * 16 + m) * 6;
#pragma unroll
      for (int c = 0; c < 6; ++c) a[c] = (short)f2bf(wr[c]);
    }
    w0f[ot] = a;
  }

  f32x4 ssum[C2 / 16], ssq[C2 / 16];
#pragma unroll
  for (int ot = 0; ot < C2 / 16; ++ot) {
    ssum[ot] = (f32x4)(0.f);
    ssq[ot] = (f32x4)(0.f);
  }

  __syncthreads();

#pragma unroll 1
  for (int kc = 0; kc < NKC; ++kc) {
    bf16x8 b1 = (bf16x8)(short)0;
    float nf[6] = {0, 0, 0, 0, 0, 0};
    if (g == 0) {
      b1[0] = (short)f2bf(pf[0]);
      b1[1] = (short)f2bf(pf[1]);
      b1[2] = (short)f2bf(pf[2]);
      b1[3] = (short)f2bf(pf[3] - cx0);
      b1[4] = (short)f2bf(pf[4] - cx1);
      b1[5] = (short)f2bf(pf[5] - cx2);
      int jn = jB;
      int kc2 = (kc + 2 < NKC) ? kc + 2 : NKC - 1;
      jB = idxp[kc2 * 8 + kl];
      nf[0] = pb[jn]; nf[1] = pb[8192 + jn]; nf[2] = pb[16384 + jn];
      nf[3] = xb[jn]; nf[4] = xb[8192 + jn]; nf[5] = xb[16384 + jn];
    }

    f32x4 acc0[C1 / 16];
#pragma unroll
    for (int ot = 0; ot < C1 / 16; ++ot)
      acc0[ot] = __builtin_amdgcn_mfma_f32_16x16x32_bf16(w0f[ot], b1, (f32x4)(0.f), 0, 0, 0);
    norm_store<C1, C1P>(act1, st0n, m, g, pbase, acc0);
    f32x4 acc1[C2 / 16];
    mfma_layer<C1, C2, C1P>(act1, wl1, m, g, pbase, acc1);
#pragma unroll
    for (int ot = 0; ot < C2 / 16; ++ot)
#pragma unroll
      for (int r = 0; r < 4; ++r) {
        ssum[ot][r] += acc1[ot][r];
        ssq[ot][r] = fmaf(acc1[ot][r], acc1[ot][r], ssq[ot][r]);
      }
#pragma unroll
    for (int i = 0; i < 6; ++i) pf[i] = nf[i];
  }

#pragma unroll
  for (int ot = 0; ot < C2 / 16; ++ot)
#pragma unroll
    for (int r = 0; r < 4; ++r)
#pragma unroll
      for (int msk = 1; msk < 16; msk <<= 1) {
        ssum[ot][r] += __shfl_xor(ssum[ot][r], msk);
        ssq[ot][r] += __shfl_xor(ssq[ot][r], msk);
      }

  __syncthreads();  // act1 dead -> epilogue overlay
  for (int i = tid; i < C2 * 2; i += 256) statbuf[i] = 0.f;
  __syncthreads();
  if (m == 0) {
#pragma unroll
    for (int ot = 0; ot < C2 / 16; ++ot)
#pragma unroll
      for (int r = 0; r < 4; ++r) {
        atomicAdd(&statbuf[ot * 16 + g * 4 + r], ssum[ot][r]);
        atomicAdd(&statbuf[C2 + ot * 16 + g * 4 + r], ssq[ot][r]);
      }
  }
  __syncthreads();
  for (int i = tid; i < C2 * 2; i += 256)
    atomicAdd(stOut + (i < C2 ? i : 128 + (i - C2)), statbuf[i]);
}

__global__ __launch_bounds__(256, 3) void fused2_kernel(
    const float* __restrict__ xyz, const float* __restrict__ pts,
    const int* __restrict__ idx, PWB pw, float* __restrict__ stats) {
  __shared__ __align__(16) char smem[24064];
  const int sc = blockIdx.z;
  if (sc == 0)
    fused2_body<32, 32, 16>(xyz, pts, idx, pw.W[0][0], pw.W[0][1], stats, smem);
  else if (sc == 1)
    fused2_body<64, 64, 32>(xyz, pts, idx, pw.W[1][0], pw.W[1][1], stats + 1536, smem);
  else
    fused2_body<64, 96, 128>(xyz, pts, idx, pw.W[2][0], pw.W[2][1], stats + 3072, smem);
}

// ---------------- fused3: L1+L2 recompute (p-split) + L3 ot-split ----------
// Double-buffered a2: ONE barrier per kc; L3(kc) overlaps L1/L2(kc+1) across
// waves.  Waves own p-tiles for L1/L2; for L3 each wave owns C3/4 output
// channels with W2 fragments in registers, reading the full a2 tile from LDS.
template <int C1, int C2, int C3, int K>
__device__ __forceinline__ void fused3_body(
    const float* __restrict__ xyz, const float* __restrict__ pts,
    const int* __restrict__ idx,
    const float* __restrict__ W0g, const float* __restrict__ W1g,
    const float* __restrict__ W2g,
    float* __restrict__ sb, unsigned short* __restrict__ maxz, int choff,
    char* __restrict__ smem) {
  constexpr int C1P = C1 + 8;
  constexpr int C2P = C2 + 8;
  constexpr int WL1E = C2 * C1P;
  constexpr int ACT1E = 64 * C1P;
  constexpr int ACT2E = 64 * C2P;
  constexpr int NOT3 = C3 / 64;   // L3 out-tiles per wave
  constexpr int NKS3 = C2 / 32;

  unsigned short* wl1 = (unsigned short*)smem;
  unsigned short* act1 = wl1 + WL1E;
  unsigned short* act2base = act1 + ACT1E;   // [2][ACT2E]
  float* st0n = (float*)((char*)(act2base + 2 * ACT2E));
  float* st1n = st0n + 2 * C1;
  float* maxbuf = (float*)act1;            // epilogue overlay [C3*8]
  float* statbuf = (float*)act1 + C3 * 8;  // [C3*2]
  float* stOut = sb + 1024;

  const int tid = threadIdx.x;
  const int lane = tid & 63;
  const int w = tid >> 6;
  const int m = lane & 15, g = lane >> 4;
  const int s0 = blockIdx.x * 8;
  const int b = blockIdx.y;
  const int pbase = w * 16;

  const int p = pbase + m;
  const int kl = p >> 3;
  const int s = s0 + (p & 7);
  const float* xb = xyz + (size_t)b * 24576;
  const float* pb = pts + (size_t)b * 24576;
  const int* idxp = idx + (((size_t)b * 1024 + s) << 7);
  float cx0 = 0.f, cx1 = 0.f, cx2 = 0.f;
  if (g == 0) {
    cx0 = xb[s];
    cx1 = xb[8192 + s];
    cx2 = xb[16384 + s];
  }

  constexpr int NKC = K / 8;
  float pf[6] = {0, 0, 0, 0, 0, 0};
  int jB = 0;
  if (g == 0) {
    int j0 = idxp[kl];
    pf[0] = pb[j0]; pf[1] = pb[8192 + j0]; pf[2] = pb[16384 + j0];
    pf[3] = xb[j0]; pf[4] = xb[8192 + j0]; pf[5] = xb[16384 + j0];
    jB = idxp[(NKC > 1 ? 8 : 0) + kl];
  }

  // stage W1 (LDS) and norm params
  for (int i = tid; i < C2 * C1; i += 256) {
    int o = i / C1, c = i - o * C1;
    wl1[o * C1P + c] = f2bf(W1g[i]);
  }
  for (int i = tid; i < C1; i += 256) {
    st0n[i] = sb[256 + i];
    st0n[C1 + i] = sb[384 + i];
  }
  for (int i = tid; i < C2; i += 256) {
    st1n[i] = sb[512 + 256 + i];
    st1n[C2 + i] = sb[512 + 384 + i];
  }

  // W0 fragments (registers)
  bf16x8 w0f[C1 / 16];
#pragma unroll
  for (int ot = 0; ot < C1 / 16; ++ot) {
    bf16x8 a = (bf16x8)(short)0;
    if (g == 0) {
      const float* wr = W0g + (ot * 16 + m) * 6;
#pragma unroll
      for (int c = 0; c < 6; ++c) a[c] = (short)f2bf(wr[c]);
    }
    w0f[ot] = a;
  }
  // W2 fragments (registers): wave w owns channels [w*16*NOT3, ...)
  bf16x8 w2f[NOT3][NKS3];
#pragma unroll
  for (int ot = 0; ot < NOT3; ++ot)
#pragma unroll
    for (int ks = 0; ks < NKS3; ++ks) {
      const float* wr = W2g + (size_t)((w * NOT3 + ot) * 16 + m) * C2 + ks * 32 + g * 8;
      bf16x8 a;
#pragma unroll
      for (int i = 0; i < 8; ++i) a[i] = (short)f2bf(wr[i]);
      w2f[ot][ks] = a;
    }

  f32x4 ssum[NOT3], ssq[NOT3], mx[NOT3];
#pragma unroll
  for (int ot = 0; ot < NOT3; ++ot) {
    ssum[ot] = (f32x4)(0.f);
    ssq[ot] = (f32x4)(0.f);
    mx[ot] = (f32x4)(-3.4e38f);
  }

  __syncthreads();

#pragma unroll 1
  for (int kc = 0; kc < NKC; ++kc) {
    unsigned short* act2 = act2base + (kc & 1) * ACT2E;
    bf16x8 b1 = (bf16x8)(short)0;
    float nf[6] = {0, 0, 0, 0, 0, 0};
    if (g == 0) {
      b1[0] = (short)f2bf(pf[0]);
      b1[1] = (short)f2bf(pf[1]);
      b1[2] = (short)f2bf(pf[2]);
      b1[3] = (short)f2bf(pf[3] - cx0);
      b1[4] = (short)f2bf(pf[4] - cx1);
      b1[5] = (short)f2bf(pf[5] - cx2);
      int jn = jB;
      int kc2 = (kc + 2 < NKC) ? kc + 2 : NKC - 1;
      jB = idxp[kc2 * 8 + kl];
      nf[0] = pb[jn]; nf[1] = pb[8192 + jn]; nf[2] = pb[16384 + jn];
      nf[3] = xb[jn]; nf[4] = xb[8192 + jn]; nf[5] = xb[16384 + jn];
    }

    // L1 (p-split, wave-local)
    f32x4 acc0[C1 / 16];
#pragma unroll
    for (int ot = 0; ot < C1 / 16; ++ot)
      acc0[ot] = __builtin_amdgcn_mfma_f32_16x16x32_bf16(w0f[ot], b1, (f32x4)(0.f), 0, 0, 0);
    norm_store<C1, C1P>(act1, st0n, m, g, pbase, acc0);
    // L2 (p-split, wave-local)
    f32x4 acc1[C2 / 16];
    mfma_layer<C1, C2, C1P>(act1, wl1, m, g, pbase, acc1);
    norm_store<C2, C2P>(act2, st1n, m, g, pbase, acc1);
    __syncthreads();  // a2[kc&1] complete across waves (double-buffer: safe)

    // L3 (ot-split): all 4 p-subtiles, weights in registers
#pragma unroll
    for (int pt = 0; pt < 4; ++pt) {
      f32x4 acc2[NOT3];
#pragma unroll
      for (int ot = 0; ot < NOT3; ++ot) acc2[ot] = (f32x4)(0.f);
#pragma unroll
      for (int ks = 0; ks < NKS3; ++ks) {
        const bf16x8 bf = *(const bf16x8*)(act2 + (pt * 16 + m) * C2P + ks * 32 + g * 8);
#pragma unroll
        for (int ot = 0; ot < NOT3; ++ot)
          acc2[ot] = __builtin_amdgcn_mfma_f32_16x16x32_bf16(w2f[ot][ks], bf, acc2[ot], 0, 0, 0);
      }
#pragma unroll
      for (int ot = 0; ot < NOT3; ++ot)
#pragma unroll
        for (int r = 0; r < 4; ++r) {
          float v = acc2[ot][r];
          ssum[ot][r] += v;
          ssq[ot][r] = fmaf(v, v, ssq[ot][r]);
          mx[ot][r] = fmaxf(mx[ot][r], v);
        }
    }
    // no trailing barrier: next iteration writes the other a2 buffer; the
    // next barrier orders reuse of this one.
#pragma unroll
    for (int i = 0; i < 6; ++i) pf[i] = nf[i];
  }

  // ---- epilogue: reduce over 16 m-lanes (positions); channels disjoint ----
#pragma unroll
  for (int ot = 0; ot < NOT3; ++ot)
#pragma unroll
    for (int r = 0; r < 4; ++r) {
#pragma unroll
      for (int msk = 1; msk < 16; msk <<= 1) {
        ssum[ot][r] += __shfl_xor(ssum[ot][r], msk);
        ssq[ot][r] += __shfl_xor(ssq[ot][r], msk);
      }
      mx[ot][r] = fmaxf(mx[ot][r], __shfl_xor(mx[ot][r], 8));  // kl-pair, same s
    }

  __syncthreads();  // all waves past final L3 before act1 overlay is written
  // plain LDS writes: each (ch) / (ch,sl) owned by exactly one lane
  if (m == 0) {
#pragma unroll
    for (int ot = 0; ot < NOT3; ++ot) {
      int ch0 = (w * NOT3 + ot) * 16 + g * 4;
      *(f32x4*)(statbuf + ch0) = ssum[ot];
      *(f32x4*)(statbuf + C3 + ch0) = ssq[ot];
    }
  }
  if (m < 8) {
#pragma unroll
    for (int ot = 0; ot < NOT3; ++ot)
#pragma unroll
      for (int r = 0; r < 4; ++r)
        maxbuf[((w * NOT3 + ot) * 16 + g * 4 + r) * 8 + m] = mx[ot][r];
  }
  __syncthreads();

  for (int i = tid; i < C3 * 2; i += 256)
    atomicAdd(stOut + (i < C3 ? i : 128 + (i - C3)), statbuf[i]);
  for (int i = tid; i < C3 * 8; i += 256) {
    int ch = i >> 3, sl = i & 7;
    maxz[(((size_t)b * 320 + choff + ch) << 10) + s0 + sl] = f2bf(maxbuf[i]);
  }
}

__global__ __launch_bounds__(256, 3) void fused3_kernel(
    const float* __restrict__ xyz, const float* __restrict__ pts,
    const int* __restrict__ idx, PWB pw, float* __restrict__ stats,
    unsigned short* __restrict__ maxz) {
  // max: scale2 = wl1 13824 + act1 9216 + 2*act2 26624 + stn 1280 = 50944 B
  __shared__ __align__(16) char smem[50944];
  const int sc = blockIdx.z;
  if (sc == 0)
    fused3_body<32, 32, 64, 16>(xyz, pts, idx, pw.W[0][0], pw.W[0][1], pw.W[0][2],
                                stats, maxz, 0, smem);
  else if (sc == 1)
    fused3_body<64, 64, 128, 32>(xyz, pts, idx, pw.W[1][0], pw.W[1][1], pw.W[1][2],
                                 stats + 1536, maxz, 64, smem);
  else
    fused3_body<64, 96, 128, 128>(xyz, pts, idx, pw.W[2][0], pw.W[2][1], pw.W[2][2],
                                  stats + 3072, maxz, 192, smem);
}

// ---------------- merged finalize ----------------
__global__ void finalize_layer_kernel(float* __restrict__ stats, int layerOff,
                                      const float* G0, const float* Bt0,
                                      const float* G1, const float* Bt1,
                                      const float* G2, const float* Bt2,
                                      int c0, int c1, int c2) {
  const int scale = blockIdx.x;
  const int o = threadIdx.x;
  const int C = scale == 0 ? c0 : (scale == 1 ? c1 : c2);
  const float invc = scale == 0 ? (1.f / 131072.f)
                                : (scale == 1 ? (1.f / 262144.f) : (1.f / 1048576.f));
  const float* G = scale == 0 ? G0 : (scale == 1 ? G1 : G2);
  const float* Bt = scale == 0 ? Bt0 : (scale == 1 ? Bt1 : Bt2);
  float* st = stats + scale * 1536 + layerOff;
  if (o < C) {
    float mean = st[o] * invc;
    float var = st[128 + o] * invc - mean * mean;
    float sc = G[o] / sqrtf(var + 1e-5f);
    st[256 + o] = sc;
    st[384 + o] = Bt[o] - mean * sc;
  }
}

// ---------------- merged outpool: out1 = relu(sc*max_raw + shift) ----------
__global__ __launch_bounds__(256) void outpool_kernel(const unsigned short* __restrict__ maxz,
                                                      const float* __restrict__ stats,
                                                      float* __restrict__ out1) {
  const int o = blockIdx.x;
  const int b = blockIdx.y;
  const int t = threadIdx.x;
  const int scale = o < 64 ? 0 : (o < 192 ? 1 : 2);
  const int choff = scale == 0 ? 0 : (scale == 1 ? 64 : 192);
  const float* st = stats + scale * 1536 + 1024;
  const float sc = st[256 + (o - choff)], sh = st[384 + (o - choff)];
  uint2 v = *(const uint2*)(maxz + (((size_t)b * 320 + o) << 10) + t * 4);
  float4 r;
  r.x = fmaxf(fmaf(bf2f((unsigned short)(v.x & 0xFFFFu)), sc, sh), 0.f);
  r.y = fmaxf(fmaf(bf2f((unsigned short)(v.x >> 16)), sc, sh), 0.f);
  r.z = fmaxf(fmaf(bf2f((unsigned short)(v.y & 0xFFFFu)), sc, sh), 0.f);
  r.w = fmaxf(fmaf(bf2f((unsigned short)(v.y >> 16)), sc, sh), 0.f);
  *(float4*)(out1 + (((size_t)b * 320 + o) << 10) + t * 4) = r;
}

// ---------------------------------------------------------------------------
extern "C" void kernel_launch(void* const* d_in, const int* in_sizes, int n_in,
                              void* d_out, int out_size, void* d_ws, size_t ws_size,
                              hipStream_t stream) {
  const float* xyz = (const float*)d_in[0];
  const float* pts = (const float*)d_in[1];
  float* out = (float*)d_out;
  float* out1 = out + 24576;

  char* wsb = (char*)d_ws;
  int* idxb = (int*)wsb;                            // 4 MB
  float* stats = (float*)(wsb + 4194304);           // 3*1536 + 96 floats
  float* mom = stats + 4608;
  unsigned short* maxz = (unsigned short*)(wsb + 4194304 + 32768);  // 5.24 MB

  PWB pw;
  const float *GG[3][3], *BT[3][3];
  for (int i = 0; i < 3; ++i)
    for (int j = 0; j < 3; ++j) {
      int base = 2 + (i * 3 + j) * 4;
      pw.W[i][j] = (const float*)d_in[base];
      GG[i][j] = (const float*)d_in[base + 2];
      BT[i][j] = (const float*)d_in[base + 3];
    }

  zero_stats_kernel<<<1, 256, 0, stream>>>(stats);
  copyxyz_kernel<<<96, 256, 0, stream>>>(xyz, out);
  knn_kernel<<<8192, 256, 0, stream>>>(xyz, idxb);
  moment_kernel<<<dim3(32, 8), 256, 0, stream>>>(xyz, pts, idxb, mom);
  finalize0_kernel<<<1, 256, 0, stream>>>(mom, stats,
                                          pw.W[0][0], GG[0][0], BT[0][0],
                                          pw.W[1][0], GG[1][0], BT[1][0],
                                          pw.W[2][0], GG[2][0], BT[2][0]);
  const dim3 fgrid(128, 8, 3);
  fused2_kernel<<<fgrid, 256, 0, stream>>>(xyz, pts, idxb, pw, stats);
  finalize_layer_kernel<<<3, 128, 0, stream>>>(stats, 512,
                                               GG[0][1], BT[0][1], GG[1][1], BT[1][1],
                                               GG[2][1], BT[2][1], 32, 64, 96);
  fused3_kernel<<<fgrid, 256, 0, stream>>>(xyz, pts, idxb, pw, stats, maxz);
  finalize_layer_kernel<<<3, 128, 0, stream>>>(stats, 1024,
                                               GG[0][2], BT[0][2], GG[1][2], BT[1][2],
                                               GG[2][2], BT[2][2], 64, 128, 128);
  outpool_kernel<<<dim3(320, 8), 256, 0, stream>>>(maxz, stats, out1);
}

// Round 11
// 479.962 us; speedup vs baseline: 1.0186x; 1.0186x over previous
//
#include <hip/hip_runtime.h>

// ---------------------------------------------------------------------------
// PointNet++ SA-MSG on MI355X.
// KNN (top-128, reg-cached keys + rank-scatter) -> moments (L0 BN stats) ->
// fused2 (L1+L2 raw stats) -> fused3 (L1+L2 recompute + L3 ot-split across
// waves, double-buffered a2, one barrier/kc) -> finalize -> outpool.
// Conv biases are BN no-ops and dropped.  bf16 MFMA 16x16x32, fp32 accum.
// bf16 packing via v_cvt_pk_bf16_f32 (1 instr / 2 values vs ~10 sw-RNE).
// ---------------------------------------------------------------------------

typedef __attribute__((ext_vector_type(8))) short bf16x8;   // 8 bf16 = 4 VGPR
typedef __attribute__((ext_vector_type(4))) float f32x4;

__device__ __forceinline__ float bf2f(unsigned short u) {
  return __uint_as_float(((unsigned)u) << 16);
}
__device__ __forceinline__ unsigned short f2bf(float f) {
  unsigned u = __float_as_uint(f);
  unsigned r = (u + 0x7FFFu + ((u >> 16) & 1u)) >> 16;  // RNE
  return (unsigned short)r;
}
// HW packed f32x2 -> bf16x2 (RNE), lo in [15:0], hi in [31:16]
__device__ __forceinline__ unsigned cvtpk2(float lo, float hi) {
  unsigned r;
  asm("v_cvt_pk_bf16_f32 %0, %1, %2" : "=v"(r) : "v"(lo), "v"(hi));
  return r;
}

struct PWB { const float* W[3][3]; };

// ---------------- out0 = xyz[:, :, :1024]  (+ zero stats in block 0) -------
__global__ void copyxyz_kernel(const float* __restrict__ xyz, float* __restrict__ out,
                               float* __restrict__ stats) {
  if (blockIdx.x == 0) {
    for (int i = threadIdx.x; i < 4704; i += 256) stats[i] = 0.f;
  }
  int t = blockIdx.x * 256 + threadIdx.x;  // 24576 total
  int b = t / 3072;
  int r = t - b * 3072;
  int c = r >> 10, s = r & 1023;
  out[t] = xyz[(size_t)(b * 3 + c) * 8192 + s];
}

// ---------------- KNN: top-128 by (d, idx) ----------------
// Keys cached in registers (32/thread, statically unrolled). Histogram select
// -> collect candidates -> rank-by-counting scatter (exact numpy tie-break).
__global__ __launch_bounds__(256) void knn_kernel(const float* __restrict__ xyz,
                                                  int* __restrict__ idxout) {
  __shared__ unsigned hist[4096];            // 16 KB
  __shared__ unsigned long long sbuf[512];   // 4 KB
  __shared__ unsigned wsum[4];
  __shared__ unsigned selB, selC;
  __shared__ int cnt;

  const int tid = threadIdx.x;
  const int lane = tid & 63;
  const int wid = tid >> 6;
  const int bs = blockIdx.x;
  const int b = bs >> 10, s = bs & 1023;
  const float* xb = xyz + (size_t)b * 3 * 8192;

  const float q0 = xb[s], q1 = xb[8192 + s], q2 = xb[16384 + s];
  const float qq =
      __fadd_rn(__fadd_rn(__fmul_rn(q0, q0), __fmul_rn(q1, q1)), __fmul_rn(q2, q2));

  auto ckey = [&](int n) -> unsigned {
    float p0 = xb[n], p1 = xb[8192 + n], p2 = xb[16384 + n];
    float pp = __fadd_rn(__fadd_rn(__fmul_rn(p0, p0), __fmul_rn(p1, p1)), __fmul_rn(p2, p2));
    float dot =
        __fadd_rn(__fadd_rn(__fmul_rn(q0, p0), __fmul_rn(q1, p1)), __fmul_rn(q2, p2));
    float dd = __fadd_rn(__fadd_rn(qq, pp), __fmul_rn(-2.f, dot));
    unsigned uu = __float_as_uint(dd);
    return (uu & 0x80000000u) ? ~uu : (uu | 0x80000000u);
  };

  auto select_bin = [&](int rank) {
    unsigned psum = 0;
#pragma unroll
    for (int i = 0; i < 16; ++i) psum += hist[tid * 16 + i];
    unsigned sc = psum;
#pragma unroll
    for (int d = 1; d < 64; d <<= 1) {
      unsigned v = __shfl_up(sc, d);
      if (lane >= d) sc += v;
    }
    if (lane == 63) wsum[wid] = sc;
    __syncthreads();
    unsigned excl = sc - psum;
#pragma unroll
    for (int w2 = 0; w2 < 3; ++w2)
      if (w2 < wid) excl += wsum[w2];
    unsigned incl = excl + psum;
    if ((unsigned)rank >= excl && (unsigned)rank < incl) {
      unsigned cum = excl;
      int bsel = tid * 16;
#pragma unroll
      for (int i = 0; i < 16; ++i) {
        unsigned h = hist[tid * 16 + i];
        if (cum + h > (unsigned)rank) { bsel = tid * 16 + i; break; }
        cum += h;
      }
      selB = (unsigned)bsel;
      selC = cum;
    }
    __syncthreads();
  };

  for (int i = tid; i < 4096; i += 256) hist[i] = 0;
  if (tid == 0) cnt = 0;
  __syncthreads();

  // pass A: compute keys once (registers), histogram bits [31:20]
  unsigned kreg[32];
#pragma unroll
  for (int i = 0; i < 32; ++i) {
    kreg[i] = ckey(tid + i * 256);
    atomicAdd(&hist[kreg[i] >> 20], 1u);
  }
  __syncthreads();

  select_bin(127);
  const unsigned B1 = selB, c1 = selC;
  const unsigned h1 = hist[B1];
  unsigned T24;
  if (c1 + h1 <= 512) {
    T24 = (B1 << 12) | 0xFFFu;  // whole bin (common case)
  } else {
    // rare: refine on bits [19:8] within bin B1 (keys already in registers)
    __syncthreads();
    for (int i = tid; i < 4096; i += 256) hist[i] = 0;
    __syncthreads();
#pragma unroll
    for (int i = 0; i < 32; ++i)
      if ((kreg[i] >> 20) == B1) atomicAdd(&hist[(kreg[i] >> 8) & 0xFFFu], 1u);
    __syncthreads();
    select_bin(127 - (int)c1);
    T24 = (B1 << 12) | selB;
  }

  // collect candidates (superset of top-128), composite (key<<13)|idx
#pragma unroll
  for (int i = 0; i < 32; ++i) {
    unsigned key = kreg[i];
    if ((key >> 8) <= T24) {
      int pos = atomicAdd(&cnt, 1);
      if (pos < 512) sbuf[pos] = (((unsigned long long)key) << 13) | (unsigned)(tid + i * 256);
    }
  }
  __syncthreads();
  const int cc = cnt < 512 ? cnt : 512;

  // rank-by-counting: keys distinct -> exact rank; write top-128 by rank.
  for (int e = tid; e < cc; e += 256) {
    const unsigned long long mykey = sbuf[e];
    int rank = 0;
    for (int j = 0; j < cc; ++j) rank += (sbuf[j] < mykey) ? 1 : 0;  // LDS broadcast
    if (rank < 128) idxout[(size_t)bs * 128 + rank] = (int)(mykey & 0x1FFFu);
  }
}

// ---------------- moment pass: per-segment Σv, Σv⊗v over gathered sets -----
__global__ __launch_bounds__(256) void moment_kernel(const float* __restrict__ xyz,
                                                     const float* __restrict__ pts,
                                                     const int* __restrict__ idx,
                                                     float* __restrict__ mom) {
  __shared__ float msum[81];
  const int tid = threadIdx.x;
  for (int i = tid; i < 81; i += 256) msum[i] = 0.f;
  __syncthreads();
  const int b = blockIdx.y;
  const int s = blockIdx.x * 32 + (tid >> 3);
  const int kseg = tid & 7;
  const int seg = kseg == 0 ? 0 : (kseg == 1 ? 1 : 2);
  const float* xb = xyz + (size_t)b * 24576;
  const float* pb = pts + (size_t)b * 24576;
  const int* ip = idx + (((size_t)b * 1024 + s) << 7) + kseg * 16;
  const float q0 = xb[s], q1 = xb[8192 + s], q2 = xb[16384 + s];
  float a[27];
#pragma unroll
  for (int i = 0; i < 27; ++i) a[i] = 0.f;
#pragma unroll 4
  for (int kk = 0; kk < 16; ++kk) {
    int j = ip[kk];
    float v[6];
    v[0] = pb[j]; v[1] = pb[8192 + j]; v[2] = pb[16384 + j];
    v[3] = xb[j] - q0; v[4] = xb[8192 + j] - q1; v[5] = xb[16384 + j] - q2;
    int p = 6;
#pragma unroll
    for (int aa = 0; aa < 6; ++aa) {
      a[aa] += v[aa];
#pragma unroll
      for (int cc = aa; cc < 6; ++cc) a[p++] = fmaf(v[aa], v[cc], a[p]);
    }
  }
#pragma unroll
  for (int i = 0; i < 27; ++i) atomicAdd(&msum[seg * 27 + i], a[i]);
  __syncthreads();
  for (int i = tid; i < 81; i += 256) atomicAdd(&mom[i], msum[i]);
}

// ---------------- finalize layer-0 stats from moments ----------------
__global__ void finalize0_kernel(const float* __restrict__ mom, float* __restrict__ stats,
                                 const float* W00, const float* G00, const float* BB00,
                                 const float* W10, const float* G10, const float* BB10,
                                 const float* W20, const float* G20, const float* BB20) {
  __shared__ float S[3][27];
  const int t = threadIdx.x;
  if (t < 27) {
    float p0 = mom[t], p1 = mom[27 + t], p2 = mom[54 + t];
    S[0][t] = p0;
    S[1][t] = p0 + p1;
    S[2][t] = p0 + p1 + p2;
  }
  __syncthreads();
  if (t >= 160) return;
  int scale, ch;
  const float *W, *G, *BB;
  float N;
  if (t < 32) { scale = 0; ch = t; W = W00; G = G00; BB = BB00; N = 131072.f; }
  else if (t < 96) { scale = 1; ch = t - 32; W = W10; G = G10; BB = BB10; N = 262144.f; }
  else { scale = 2; ch = t - 96; W = W20; G = G20; BB = BB20; N = 1048576.f; }
  float w[6];
#pragma unroll
  for (int c = 0; c < 6; ++c) w[c] = W[ch * 6 + c];
  const float* Sv = S[scale];
  float wS1 = 0.f;
#pragma unroll
  for (int c = 0; c < 6; ++c) wS1 = fmaf(w[c], Sv[c], wS1);
  float quad = 0.f;
  int p = 6;
#pragma unroll
  for (int aa = 0; aa < 6; ++aa)
#pragma unroll
    for (int cc = aa; cc < 6; ++cc) {
      float coef = (aa == cc) ? w[aa] * w[aa] : 2.f * w[aa] * w[cc];
      quad = fmaf(coef, Sv[p++], quad);
    }
  float mean = wS1 / N;
  float var = quad / N - mean * mean;
  float sc = G[ch] / sqrtf(var + 1e-5f);
  stats[scale * 1536 + 256 + ch] = sc;
  stats[scale * 1536 + 384 + ch] = BB[ch] - mean * sc;
}

// ---------------- MFMA helpers ----------------
// 16x16x32: A: lane A[l&15][(l>>4)*8+i]; B: B[(l>>4)*8+i][l&15];
// D: row=(l>>4)*4+r, col=l&15.
template <int CIN, int COUT, int CINP>
__device__ __forceinline__ void mfma_layer(const unsigned short* __restrict__ act,
                                           const unsigned short* __restrict__ wl,
                                           int m, int g, int pbase, f32x4* acc) {
#pragma unroll
  for (int ot = 0; ot < COUT / 16; ++ot) acc[ot] = (f32x4)(0.f);
#pragma unroll
  for (int ks = 0; ks < CIN / 32; ++ks) {
    const bf16x8 bfrag = *(const bf16x8*)(act + (pbase + m) * CINP + ks * 32 + g * 8);
#pragma unroll
    for (int ot = 0; ot < COUT / 16; ++ot) {
      const bf16x8 afrag = *(const bf16x8*)(wl + (ot * 16 + m) * CINP + ks * 32 + g * 8);
      acc[ot] = __builtin_amdgcn_mfma_f32_16x16x32_bf16(afrag, bfrag, acc[ot], 0, 0, 0);
    }
  }
}

template <int COUT, int COUTP>
__device__ __forceinline__ void norm_store(unsigned short* __restrict__ dst,
                                           const float* __restrict__ stn,
                                           int m, int g, int pbase, const f32x4* acc) {
#pragma unroll
  for (int ot = 0; ot < COUT / 16; ++ot) {
    const int ch = ot * 16 + g * 4;
    f32x4 sc = *(const f32x4*)(stn + ch);
    f32x4 sh = *(const f32x4*)(stn + COUT + ch);
    float v0 = fmaxf(fmaf(acc[ot][0], sc[0], sh[0]), 0.f);
    float v1 = fmaxf(fmaf(acc[ot][1], sc[1], sh[1]), 0.f);
    float v2 = fmaxf(fmaf(acc[ot][2], sc[2], sh[2]), 0.f);
    float v3 = fmaxf(fmaf(acc[ot][3], sc[3], sh[3]), 0.f);
    uint2 pv = make_uint2(cvtpk2(v0, v1), cvtpk2(v2, v3));
    *(uint2*)(dst + (pbase + m) * COUTP + ch) = pv;
  }
}

// build gather B-fragment: 6 bf16 values in lanes g==0, zeros elsewhere
__device__ __forceinline__ bf16x8 gather_frag(const float* pf, float cx0, float cx1,
                                              float cx2, int g) {
  union { bf16x8 v; unsigned u[4]; } ub;
  ub.u[0] = ub.u[1] = ub.u[2] = ub.u[3] = 0u;
  if (g == 0) {
    ub.u[0] = cvtpk2(pf[0], pf[1]);
    ub.u[1] = cvtpk2(pf[2], pf[3] - cx0);
    ub.u[2] = cvtpk2(pf[4] - cx1, pf[5] - cx2);
  }
  return ub.v;
}

// ---------------- fused2: L1 -> norm -> L2, raw h1 stats ----------------
template <int C1, int C2, int K>
__device__ __forceinline__ void fused2_body(
    const float* __restrict__ xyz, const float* __restrict__ pts,
    const int* __restrict__ idx,
    const float* __restrict__ W0g, const float* __restrict__ W1g,
    float* __restrict__ sb, char* __restrict__ smem) {
  constexpr int C1P = C1 + 8;
  constexpr int WL1E = C2 * C1P;
  constexpr int ACT1E = 64 * C1P;
  constexpr int EPIB = C2 * 2 * 4;
  constexpr int ACTB = (ACT1E * 2 > EPIB) ? ACT1E * 2 : EPIB;

  unsigned short* wl1 = (unsigned short*)smem;
  unsigned short* act1 = wl1 + WL1E;
  float* st0n = (float*)(smem + WL1E * 2 + ACTB);
  float* statbuf = (float*)act1;  // epilogue overlay [2*C2]
  float* stOut = sb + 512;

  const int tid = threadIdx.x;
  const int lane = tid & 63;
  const int w = tid >> 6;
  const int m = lane & 15, g = lane >> 4;
  const int s0 = blockIdx.x * 8;
  const int b = blockIdx.y;
  const int pbase = w * 16;

  const int p = pbase + m;
  const int kl = p >> 3;
  const int s = s0 + (p & 7);
  const float* xb = xyz + (size_t)b * 24576;
  const float* pb = pts + (size_t)b * 24576;
  const int* idxp = idx + (((size_t)b * 1024 + s) << 7);
  float cx0 = 0.f, cx1 = 0.f, cx2 = 0.f;
  if (g == 0) {
    cx0 = xb[s];
    cx1 = xb[8192 + s];
    cx2 = xb[16384 + s];
  }

  constexpr int NKC = K / 8;
  float pf[6] = {0, 0, 0, 0, 0, 0};
  int jB = 0;
  if (g == 0) {
    int j0 = idxp[kl];
    pf[0] = pb[j0]; pf[1] = pb[8192 + j0]; pf[2] = pb[16384 + j0];
    pf[3] = xb[j0]; pf[4] = xb[8192 + j0]; pf[5] = xb[16384 + j0];
    jB = idxp[(NKC > 1 ? 8 : 0) + kl];
  }

  for (int i = tid; i < C2 * C1; i += 256) {
    int o = i / C1, c = i - o * C1;
    wl1[o * C1P + c] = f2bf(W1g[i]);
  }
  for (int i = tid; i < C1; i += 256) {
    st0n[i] = sb[256 + i];
    st0n[C1 + i] = sb[384 + i];
  }

  bf16x8 w0f[C1 / 16];
#pragma unroll
  for (int ot = 0; ot < C1 / 16; ++ot) {
    bf16x8 a = (bf16x8)(short)0;
    if (g == 0) {
      const float* wr = W0g + (ot * 16 + m) * 6;
#pragma unroll
      for (int c = 0; c < 6; ++c) a[c] = (short)f2bf(wr[c]);
    }
    w0f[ot] = a;
  }

  f32x4 ssum[C2 / 16], ssq[C2 / 16];
#pragma unroll
  for (int ot = 0; ot < C2 / 16; ++ot) {
    ssum[ot] = (f32x4)(0.f);
    ssq[ot] = (f32x4)(0.f);
  }

  __syncthreads();

#pragma unroll 1
  for (int kc = 0; kc < NKC; ++kc) {
    bf16x8 b1 = gather_frag(pf, cx0, cx1, cx2, g);
    float nf[6] = {0, 0, 0, 0, 0, 0};
    if (g == 0) {
      int jn = jB;
      int kc2 = (kc + 2 < NKC) ? kc + 2 : NKC - 1;
      jB = idxp[kc2 * 8 + kl];
      nf[0] = pb[jn]; nf[1] = pb[8192 + jn]; nf[2] = pb[16384 + jn];
      nf[3] = xb[jn]; nf[4] = xb[8192 + jn]; nf[5] = xb[16384 + jn];
    }

    f32x4 acc0[C1 / 16];
#pragma unroll
    for (int ot = 0; ot < C1 / 16; ++ot)
      acc0[ot] = __builtin_amdgcn_mfma_f32_16x16x32_bf16(w0f[ot], b1, (f32x4)(0.f), 0, 0, 0);
    norm_store<C1, C1P>(act1, st0n, m, g, pbase, acc0);
    f32x4 acc1[C2 / 16];
    mfma_layer<C1, C2, C1P>(act1, wl1, m, g, pbase, acc1);
#pragma unroll
    for (int ot = 0; ot < C2 / 16; ++ot)
#pragma unroll
      for (int r = 0; r < 4; ++r) {
        ssum[ot][r] += acc1[ot][r];
        ssq[ot][r] = fmaf(acc1[ot][r], acc1[ot][r], ssq[ot][r]);
      }
#pragma unroll
    for (int i = 0; i < 6; ++i) pf[i] = nf[i];
  }

#pragma unroll
  for (int ot = 0; ot < C2 / 16; ++ot)
#pragma unroll
    for (int r = 0; r < 4; ++r)
#pragma unroll
      for (int msk = 1; msk < 16; msk <<= 1) {
        ssum[ot][r] += __shfl_xor(ssum[ot][r], msk);
        ssq[ot][r] += __shfl_xor(ssq[ot][r], msk);
      }

  __syncthreads();  // act1 dead -> epilogue overlay
  for (int i = tid; i < C2 * 2; i += 256) statbuf[i] = 0.f;
  __syncthreads();
  if (m == 0) {
#pragma unroll
    for (int ot = 0; ot < C2 / 16; ++ot)
#pragma unroll
      for (int r = 0; r < 4; ++r) {
        atomicAdd(&statbuf[ot * 16 + g * 4 + r], ssum[ot][r]);
        atomicAdd(&statbuf[C2 + ot * 16 + g * 4 + r], ssq[ot][r]);
      }
  }
  __syncthreads();
  for (int i = tid; i < C2 * 2; i += 256)
    atomicAdd(stOut + (i < C2 ? i : 128 + (i - C2)), statbuf[i]);
}

__global__ __launch_bounds__(256, 3) void fused2_kernel(
    const float* __restrict__ xyz, const float* __restrict__ pts,
    const int* __restrict__ idx, PWB pw, float* __restrict__ stats) {
  __shared__ __align__(16) char smem[24064];
  const int sc = blockIdx.z;
  if (sc == 0)
    fused2_body<32, 32, 16>(xyz, pts, idx, pw.W[0][0], pw.W[0][1], stats, smem);
  else if (sc == 1)
    fused2_body<64, 64, 32>(xyz, pts, idx, pw.W[1][0], pw.W[1][1], stats + 1536, smem);
  else
    fused2_body<64, 96, 128>(xyz, pts, idx, pw.W[2][0], pw.W[2][1], stats + 3072, smem);
}

// ---------------- fused3: L1+L2 recompute (p-split) + L3 ot-split ----------
// Double-buffered a2: ONE barrier per kc; L3(kc) overlaps L1/L2(kc+1) across
// waves.  Waves own p-tiles for L1/L2; for L3 each wave owns C3/4 output
// channels with W2 fragments in registers, reading the full a2 tile from LDS.
template <int C1, int C2, int C3, int K>
__device__ __forceinline__ void fused3_body(
    const float* __restrict__ xyz, const float* __restrict__ pts,
    const int* __restrict__ idx,
    const float* __restrict__ W0g, const float* __restrict__ W1g,
    const float* __restrict__ W2g,
    float* __restrict__ sb, unsigned short* __restrict__ maxz, int choff,
    char* __restrict__ smem) {
  constexpr int C1P = C1 + 8;
  constexpr int C2P = C2 + 8;
  constexpr int WL1E = C2 * C1P;
  constexpr int ACT1E = 64 * C1P;
  constexpr int ACT2E = 64 * C2P;
  constexpr int NOT3 = C3 / 64;   // L3 out-tiles per wave
  constexpr int NKS3 = C2 / 32;

  unsigned short* wl1 = (unsigned short*)smem;
  unsigned short* act1 = wl1 + WL1E;
  unsigned short* act2base = act1 + ACT1E;   // [2][ACT2E]
  float* st0n = (float*)((char*)(act2base + 2 * ACT2E));
  float* st1n = st0n + 2 * C1;
  float* maxbuf = (float*)act1;            // epilogue overlay [C3*8]
  float* statbuf = (float*)act1 + C3 * 8;  // [C3*2]
  float* stOut = sb + 1024;

  const int tid = threadIdx.x;
  const int lane = tid & 63;
  const int w = tid >> 6;
  const int m = lane & 15, g = lane >> 4;
  const int s0 = blockIdx.x * 8;
  const int b = blockIdx.y;
  const int pbase = w * 16;

  const int p = pbase + m;
  const int kl = p >> 3;
  const int s = s0 + (p & 7);
  const float* xb = xyz + (size_t)b * 24576;
  const float* pb = pts + (size_t)b * 24576;
  const int* idxp = idx + (((size_t)b * 1024 + s) << 7);
  float cx0 = 0.f, cx1 = 0.f, cx2 = 0.f;
  if (g == 0) {
    cx0 = xb[s];
    cx1 = xb[8192 + s];
    cx2 = xb[16384 + s];
  }

  constexpr int NKC = K / 8;
  float pf[6] = {0, 0, 0, 0, 0, 0};
  int jB = 0;
  if (g == 0) {
    int j0 = idxp[kl];
    pf[0] = pb[j0]; pf[1] = pb[8192 + j0]; pf[2] = pb[16384 + j0];
    pf[3] = xb[j0]; pf[4] = xb[8192 + j0]; pf[5] = xb[16384 + j0];
    jB = idxp[(NKC > 1 ? 8 : 0) + kl];
  }

  // stage W1 (LDS) and norm params
  for (int i = tid; i < C2 * C1; i += 256) {
    int o = i / C1, c = i - o * C1;
    wl1[o * C1P + c] = f2bf(W1g[i]);
  }
  for (int i = tid; i < C1; i += 256) {
    st0n[i] = sb[256 + i];
    st0n[C1 + i] = sb[384 + i];
  }
  for (int i = tid; i < C2; i += 256) {
    st1n[i] = sb[512 + 256 + i];
    st1n[C2 + i] = sb[512 + 384 + i];
  }

  // W0 fragments (registers)
  bf16x8 w0f[C1 / 16];
#pragma unroll
  for (int ot = 0; ot < C1 / 16; ++ot) {
    bf16x8 a = (bf16x8)(short)0;
    if (g == 0) {
      const float* wr = W0g + (ot * 16 + m) * 6;
#pragma unroll
      for (int c = 0; c < 6; ++c) a[c] = (short)f2bf(wr[c]);
    }
    w0f[ot] = a;
  }
  // W2 fragments (registers): wave w owns channels [w*16*NOT3, ...)
  bf16x8 w2f[NOT3][NKS3];
#pragma unroll
  for (int ot = 0; ot < NOT3; ++ot)
#pragma unroll
    for (int ks = 0; ks < NKS3; ++ks) {
      const float* wr = W2g + (size_t)((w * NOT3 + ot) * 16 + m) * C2 + ks * 32 + g * 8;
      bf16x8 a;
#pragma unroll
      for (int i = 0; i < 8; ++i) a[i] = (short)f2bf(wr[i]);
      w2f[ot][ks] = a;
    }

  f32x4 ssum[NOT3], ssq[NOT3], mx[NOT3];
#pragma unroll
  for (int ot = 0; ot < NOT3; ++ot) {
    ssum[ot] = (f32x4)(0.f);
    ssq[ot] = (f32x4)(0.f);
    mx[ot] = (f32x4)(-3.4e38f);
  }

  __syncthreads();

#pragma unroll 1
  for (int kc = 0; kc < NKC; ++kc) {
    unsigned short* act2 = act2base + (kc & 1) * ACT2E;
    bf16x8 b1 = gather_frag(pf, cx0, cx1, cx2, g);
    float nf[6] = {0, 0, 0, 0, 0, 0};
    if (g == 0) {
      int jn = jB;
      int kc2 = (kc + 2 < NKC) ? kc + 2 : NKC - 1;
      jB = idxp[kc2 * 8 + kl];
      nf[0] = pb[jn]; nf[1] = pb[8192 + jn]; nf[2] = pb[16384 + jn];
      nf[3] = xb[jn]; nf[4] = xb[8192 + jn]; nf[5] = xb[16384 + jn];
    }

    // L1 (p-split, wave-local)
    f32x4 acc0[C1 / 16];
#pragma unroll
    for (int ot = 0; ot < C1 / 16; ++ot)
      acc0[ot] = __builtin_amdgcn_mfma_f32_16x16x32_bf16(w0f[ot], b1, (f32x4)(0.f), 0, 0, 0);
    norm_store<C1, C1P>(act1, st0n, m, g, pbase, acc0);
    // L2 (p-split, wave-local)
    f32x4 acc1[C2 / 16];
    mfma_layer<C1, C2, C1P>(act1, wl1, m, g, pbase, acc1);
    norm_store<C2, C2P>(act2, st1n, m, g, pbase, acc1);
    __syncthreads();  // a2[kc&1] complete across waves (double-buffer: safe)

    // L3 (ot-split): all 4 p-subtiles, weights in registers
#pragma unroll
    for (int pt = 0; pt < 4; ++pt) {
      f32x4 acc2[NOT3];
#pragma unroll
      for (int ot = 0; ot < NOT3; ++ot) acc2[ot] = (f32x4)(0.f);
#pragma unroll
      for (int ks = 0; ks < NKS3; ++ks) {
        const bf16x8 bf = *(const bf16x8*)(act2 + (pt * 16 + m) * C2P + ks * 32 + g * 8);
#pragma unroll
        for (int ot = 0; ot < NOT3; ++ot)
          acc2[ot] = __builtin_amdgcn_mfma_f32_16x16x32_bf16(w2f[ot][ks], bf, acc2[ot], 0, 0, 0);
      }
#pragma unroll
      for (int ot = 0; ot < NOT3; ++ot)
#pragma unroll
        for (int r = 0; r < 4; ++r) {
          float v = acc2[ot][r];
          ssum[ot][r] += v;
          ssq[ot][r] = fmaf(v, v, ssq[ot][r]);
          mx[ot][r] = fmaxf(mx[ot][r], v);
        }
    }
    // no trailing barrier: next iteration writes the other a2 buffer; the
    // next barrier orders reuse of this one.
#pragma unroll
    for (int i = 0; i < 6; ++i) pf[i] = nf[i];
  }

  // ---- epilogue: reduce over 16 m-lanes (positions); channels disjoint ----
#pragma unroll
  for (int ot = 0; ot < NOT3; ++ot)
#pragma unroll
    for (int r = 0; r < 4; ++r) {
#pragma unroll
      for (int msk = 1; msk < 16; msk <<= 1) {
        ssum[ot][r] += __shfl_xor(ssum[ot][r], msk);
        ssq[ot][r] += __shfl_xor(ssq[ot][r], msk);
      }
      mx[ot][r] = fmaxf(mx[ot][r], __shfl_xor(mx[ot][r], 8));  // kl-pair, same s
    }

  __syncthreads();  // all waves past final L3 before act1 overlay is written
  // plain LDS writes: each (ch) / (ch,sl) owned by exactly one lane
  if (m == 0) {
#pragma unroll
    for (int ot = 0; ot < NOT3; ++ot) {
      int ch0 = (w * NOT3 + ot) * 16 + g * 4;
      *(f32x4*)(statbuf + ch0) = ssum[ot];
      *(f32x4*)(statbuf + C3 + ch0) = ssq[ot];
    }
  }
  if (m < 8) {
#pragma unroll
    for (int ot = 0; ot < NOT3; ++ot)
#pragma unroll
      for (int r = 0; r < 4; ++r)
        maxbuf[((w * NOT3 + ot) * 16 + g * 4 + r) * 8 + m] = mx[ot][r];
  }
  __syncthreads();

  for (int i = tid; i < C3 * 2; i += 256)
    atomicAdd(stOut + (i < C3 ? i : 128 + (i - C3)), statbuf[i]);
  for (int i = tid; i < C3 * 8; i += 256) {
    int ch = i >> 3, sl = i & 7;
    maxz[(((size_t)b * 320 + choff + ch) << 10) + s0 + sl] = f2bf(maxbuf[i]);
  }
}

__global__ __launch_bounds__(256, 3) void fused3_kernel(
    const float* __restrict__ xyz, const float* __restrict__ pts,
    const int* __restrict__ idx, PWB pw, float* __restrict__ stats,
    unsigned short* __restrict__ maxz) {
  // max: scale2 = wl1 13824 + act1 9216 + 2*act2 26624 + stn 1280 = 50944 B
  __shared__ __align__(16) char smem[50944];
  const int sc = blockIdx.z;
  if (sc == 0)
    fused3_body<32, 32, 64, 16>(xyz, pts, idx, pw.W[0][0], pw.W[0][1], pw.W[0][2],
                                stats, maxz, 0, smem);
  else if (sc == 1)
    fused3_body<64, 64, 128, 32>(xyz, pts, idx, pw.W[1][0], pw.W[1][1], pw.W[1][2],
                                 stats + 1536, maxz, 64, smem);
  else
    fused3_body<64, 96, 128, 128>(xyz, pts, idx, pw.W[2][0], pw.W[2][1], pw.W[2][2],
                                  stats + 3072, maxz, 192, smem);
}

// ---------------- merged finalize ----------------
__global__ void finalize_layer_kernel(float* __restrict__ stats, int layerOff,
                                      const float* G0, const float* Bt0,
                                      const float* G1, const float* Bt1,
                                      const float* G2, const float* Bt2,
                                      int c0, int c1, int c2) {
  const int scale = blockIdx.x;
  const int o = threadIdx.x;
  const int C = scale == 0 ? c0 : (scale == 1 ? c1 : c2);
  const float invc = scale == 0 ? (1.f / 131072.f)
                                : (scale == 1 ? (1.f / 262144.f) : (1.f / 1048576.f));
  const float* G = scale == 0 ? G0 : (scale == 1 ? G1 : G2);
  const float* Bt = scale == 0 ? Bt0 : (scale == 1 ? Bt1 : Bt2);
  float* st = stats + scale * 1536 + layerOff;
  if (o < C) {
    float mean = st[o] * invc;
    float var = st[128 + o] * invc - mean * mean;
    float sc = G[o] / sqrtf(var + 1e-5f);
    st[256 + o] = sc;
    st[384 + o] = Bt[o] - mean * sc;
  }
}

// ---------------- merged outpool: out1 = relu(sc*max_raw + shift) ----------
__global__ __launch_bounds__(256) void outpool_kernel(const unsigned short* __restrict__ maxz,
                                                      const float* __restrict__ stats,
                                                      float* __restrict__ out1) {
  const int o = blockIdx.x;
  const int b = blockIdx.y;
  const int t = threadIdx.x;
  const int scale = o < 64 ? 0 : (o < 192 ? 1 : 2);
  const int choff = scale == 0 ? 0 : (scale == 1 ? 64 : 192);
  const float* st = stats + scale * 1536 + 1024;
  const float sc = st[256 + (o - choff)], sh = st[384 + (o - choff)];
  uint2 v = *(const uint2*)(maxz + (((size_t)b * 320 + o) << 10) + t * 4);
  float4 r;
  r.x = fmaxf(fmaf(bf2f((unsigned short)(v.x & 0xFFFFu)), sc, sh), 0.f);
  r.y = fmaxf(fmaf(bf2f((unsigned short)(v.x >> 16)), sc, sh), 0.f);
  r.z = fmaxf(fmaf(bf2f((unsigned short)(v.y & 0xFFFFu)), sc, sh), 0.f);
  r.w = fmaxf(fmaf(bf2f((unsigned short)(v.y >> 16)), sc, sh), 0.f);
  *(float4*)(out1 + (((size_t)b * 320 + o) << 10) + t * 4) = r;
}

// ---------------------------------------------------------------------------
extern "C" void kernel_launch(void* const* d_in, const int* in_sizes, int n_in,
                              void* d_out, int out_size, void* d_ws, size_t ws_size,
                              hipStream_t stream) {
  const float* xyz = (const float*)d_in[0];
  const float* pts = (const float*)d_in[1];
  float* out = (float*)d_out;
  float* out1 = out + 24576;

  char* wsb = (char*)d_ws;
  int* idxb = (int*)wsb;                            // 4 MB
  float* stats = (float*)(wsb + 4194304);           // 3*1536 + 96 floats
  float* mom = stats + 4608;
  unsigned short* maxz = (unsigned short*)(wsb + 4194304 + 32768);  // 5.24 MB

  PWB pw;
  const float *GG[3][3], *BT[3][3];
  for (int i = 0; i < 3; ++i)
    for (int j = 0; j < 3; ++j) {
      int base = 2 + (i * 3 + j) * 4;
      pw.W[i][j] = (const float*)d_in[base];
      GG[i][j] = (const float*)d_in[base + 2];
      BT[i][j] = (const float*)d_in[base + 3];
    }

  copyxyz_kernel<<<96, 256, 0, stream>>>(xyz, out, stats);
  knn_kernel<<<8192, 256, 0, stream>>>(xyz, idxb);
  moment_kernel<<<dim3(32, 8), 256, 0, stream>>>(xyz, pts, idxb, mom);
  finalize0_kernel<<<1, 256, 0, stream>>>(mom, stats,
                                          pw.W[0][0], GG[0][0], BT[0][0],
                                          pw.W[1][0], GG[1][0], BT[1][0],
                                          pw.W[2][0], GG[2][0], BT[2][0]);
  const dim3 fgrid(128, 8, 3);
  fused2_kernel<<<fgrid, 256, 0, stream>>>(xyz, pts, idxb, pw, stats);
  finalize_layer_kernel<<<3, 128, 0, stream>>>(stats, 512,
                                               GG[0][1], BT[0][1], GG[1][1], BT[1][1],
                                               GG[2][1], BT[2][1], 32, 64, 96);
  fused3_kernel<<<fgrid, 256, 0, stream>>>(xyz, pts, idxb, pw, stats, maxz);
  finalize_layer_kernel<<<3, 128, 0, stream>>>(stats, 1024,
                                               GG[0][2], BT[0][2], GG[1][2], BT[1][2],
                                               GG[2][2], BT[2][2], 64, 128, 128);
  outpool_kernel<<<dim3(320, 8), 256, 0, stream>>>(maxz, stats, out1);
}